// Round 1
// baseline (287.337 us; speedup 1.0000x reference)
//
#include <hip/hip_runtime.h>

#define B_ROWS 16384
#define D_IN   1024
#define H_DIM  256
#define N_EXP  8
#define N_TASK 4

typedef short bf16x8 __attribute__((ext_vector_type(8)));
typedef float f32x4  __attribute__((ext_vector_type(4)));

static __device__ __forceinline__ unsigned short f2bf(float f) {
  unsigned int u = __float_as_uint(f);
  u += 0x7fffu + ((u >> 16) & 1u);   // RNE
  return (unsigned short)(u >> 16);
}
static __device__ __forceinline__ float bf2f(unsigned short u) {
  return __uint_as_float(((unsigned int)u) << 16);
}

// workspace layout (bytes)
#define WS_XB   0u          // ushort[16384*1024]  = 33,554,432 B
#define WS_WET  33554432u   // ushort[8*256*1024]  =  4,194,304 B
#define WS_WGT  37748736u   // ushort[32*1024]     =     65,536 B
#define WS_G    37814272u   // float [16384*32]    =  2,097,152 B
#define WS_E    39911424u   // ushort[16384*2048]  = 67,108,864 B

// ---------------------------------------------------------------------------
// Kernel 1: cast+transpose We -> We_t[e][h][k] bf16 ; Wg -> Wg_t[n][k] bf16
// ---------------------------------------------------------------------------
__global__ void k_prep_w(const float* __restrict__ We, const float* __restrict__ Wg,
                         unsigned short* __restrict__ We_t, unsigned short* __restrict__ Wg_t) {
  int bid = blockIdx.x;
  int t = threadIdx.x;
  if (bid < 512) {
    // one 64x64 tile of We[e]: [k][h] -> [h][k]
    int e = bid >> 6;
    int tl = bid & 63;
    int k0 = (tl >> 2) * 64, h0 = (tl & 3) * 64;
    __shared__ unsigned short tile[64][72];   // [h][k], padded
    const float* src = We + (size_t)e * (D_IN * H_DIM);
#pragma unroll
    for (int i = 0; i < 4; ++i) {
      int kk = (t >> 4) + i * 16;
      int hh = (t & 15) * 4;
      float4 v = *(const float4*)(src + (size_t)(k0 + kk) * H_DIM + h0 + hh);
      tile[hh + 0][kk] = f2bf(v.x);
      tile[hh + 1][kk] = f2bf(v.y);
      tile[hh + 2][kk] = f2bf(v.z);
      tile[hh + 3][kk] = f2bf(v.w);
    }
    __syncthreads();
    unsigned short* dst = We_t + (size_t)e * (H_DIM * D_IN);
#pragma unroll
    for (int i = 0; i < 4; ++i) {
      int hh = (t >> 4) + i * 16;
      int kk = (t & 15) * 4;
      ushort4 u = *(const ushort4*)&tile[hh][kk];
      *(ushort4*)(dst + (size_t)(h0 + hh) * D_IN + k0 + kk) = u;
    }
  } else {
    // Wg[4][1024][8] -> Wg_t[n=t*8+e][k]
    int n = t & 31;
    int kbase = (t >> 5) * 128;
    int tsk = n >> 3, e = n & 7;
    for (int i = 0; i < 128; ++i) {
      int k = kbase + i;
      Wg_t[(size_t)n * D_IN + k] = f2bf(Wg[(size_t)tsk * (D_IN * 8) + (size_t)k * 8 + e]);
    }
  }
}

// ---------------------------------------------------------------------------
// Kernel 2: per 64-row tile: cast x->bf16 (to ws), gate MFMA, softmax -> G
// ---------------------------------------------------------------------------
__global__ void k_gates(const float* __restrict__ x, const unsigned short* __restrict__ Wg_t,
                        const float* __restrict__ bg,
                        unsigned short* __restrict__ x_b, float* __restrict__ G) {
  __shared__ unsigned short xs[64][136];   // [row][k-chunk], padded
  __shared__ unsigned short wgs[32][136];  // [n][k-chunk], padded
  __shared__ float ls[64][33];             // logits
  int m0 = blockIdx.x * 64;
  int t = threadIdx.x;
  int wv = t >> 6, l = t & 63;
  f32x4 acc0 = {0.f, 0.f, 0.f, 0.f}, acc1 = {0.f, 0.f, 0.f, 0.f};

  for (int k0 = 0; k0 < D_IN; k0 += 128) {
#pragma unroll
    for (int i = 0; i < 8; ++i) {
      int r = (t >> 5) + i * 8;
      int c = (t & 31) * 4;
      float4 v = *(const float4*)(x + (size_t)(m0 + r) * D_IN + k0 + c);
      ushort4 u;
      u.x = f2bf(v.x); u.y = f2bf(v.y); u.z = f2bf(v.z); u.w = f2bf(v.w);
      *(ushort4*)&xs[r][c] = u;
      *(ushort4*)(x_b + (size_t)(m0 + r) * D_IN + k0 + c) = u;
    }
    {
      int n = t >> 3;
      int kk = (t & 7) * 16;
      const unsigned short* srcp = Wg_t + (size_t)n * D_IN + k0 + kk;
      *(ushort4*)&wgs[n][kk]      = *(const ushort4*)(srcp);
      *(ushort4*)&wgs[n][kk + 4]  = *(const ushort4*)(srcp + 4);
      *(ushort4*)&wgs[n][kk + 8]  = *(const ushort4*)(srcp + 8);
      *(ushort4*)&wgs[n][kk + 12] = *(const ushort4*)(srcp + 12);
    }
    __syncthreads();
#pragma unroll
    for (int ks = 0; ks < 4; ++ks) {
      bf16x8 a  = *(const bf16x8*)&xs[wv * 16 + (l & 15)][ks * 32 + (l >> 4) * 8];
      bf16x8 b0 = *(const bf16x8*)&wgs[(l & 15)][ks * 32 + (l >> 4) * 8];
      bf16x8 b1 = *(const bf16x8*)&wgs[16 + (l & 15)][ks * 32 + (l >> 4) * 8];
      acc0 = __builtin_amdgcn_mfma_f32_16x16x32_bf16(a, b0, acc0, 0, 0, 0);
      acc1 = __builtin_amdgcn_mfma_f32_16x16x32_bf16(a, b1, acc1, 0, 0, 0);
    }
    __syncthreads();
  }
#pragma unroll
  for (int j = 0; j < 4; ++j) {
    ls[wv * 16 + (l >> 4) * 4 + j][l & 15]      = acc0[j];
    ls[wv * 16 + (l >> 4) * 4 + j][16 + (l & 15)] = acc1[j];
  }
  __syncthreads();
  {
    int r = t >> 2, tsk = t & 3;
    float v[8]; float mx = -1e30f;
#pragma unroll
    for (int e = 0; e < 8; ++e) { v[e] = ls[r][tsk * 8 + e] + bg[tsk * 8 + e]; mx = fmaxf(mx, v[e]); }
    float s = 0.f;
#pragma unroll
    for (int e = 0; e < 8; ++e) { v[e] = __expf(v[e] - mx); s += v[e]; }
    float inv = 1.f / s;
#pragma unroll
    for (int e = 0; e < 8; ++e) G[(size_t)(m0 + r) * 32 + tsk * 8 + e] = v[e] * inv;
  }
}

// ---------------------------------------------------------------------------
// Kernel 3: expert GEMM, m97 structure. grid = m(128) x e(8) x nh(2),
// block 256 thr = 4 waves, each wave 64x64 (4x4 frags of 16x16x32 bf16).
// E[b][e*256+h] = relu(x@We + be) -> bf16 ws
// ---------------------------------------------------------------------------
__global__ __launch_bounds__(256) void k_expert(const unsigned short* __restrict__ x_b,
                                                const unsigned short* __restrict__ We_t,
                                                const float* __restrict__ be,
                                                unsigned short* __restrict__ E) {
  __shared__ unsigned short As[128 * 64];
  __shared__ unsigned short Bs[128 * 64];
  int bid = blockIdx.x;
  int m  = bid >> 4;          // same-m blocks adjacent -> spread across XCDs
  int e  = (bid >> 1) & 7;
  int nh = bid & 1;
  int m0 = m * 128;
  int t = threadIdx.x;
  int wv = t >> 6, l = t & 63;
  int wm = wv >> 1, wn = wv & 1;

  const unsigned short* Ab = x_b + (size_t)m0 * D_IN;
  const unsigned short* Bb = We_t + (size_t)e * (H_DIM * D_IN) + (size_t)(nh * 128) * D_IN;

  f32x4 acc[4][4];
#pragma unroll
  for (int i = 0; i < 4; ++i)
#pragma unroll
    for (int j = 0; j < 4; ++j) acc[i][j] = (f32x4){0.f, 0.f, 0.f, 0.f};

  int rr = t >> 3;        // 0..31
  int cc = (t & 7) * 8;   // 0..56 (bf16 elems)
  for (int k0 = 0; k0 < D_IN; k0 += 64) {
#pragma unroll
    for (int i = 0; i < 4; ++i) {
      __builtin_amdgcn_global_load_lds(
          (const __attribute__((address_space(1))) void*)(Ab + (size_t)(rr + i * 32) * D_IN + k0 + cc),
          (__attribute__((address_space(3))) void*)(As + i * 2048 + t * 8),
          16, 0, 0);
    }
#pragma unroll
    for (int i = 0; i < 4; ++i) {
      __builtin_amdgcn_global_load_lds(
          (const __attribute__((address_space(1))) void*)(Bb + (size_t)(rr + i * 32) * D_IN + k0 + cc),
          (__attribute__((address_space(3))) void*)(Bs + i * 2048 + t * 8),
          16, 0, 0);
    }
    __syncthreads();
#pragma unroll
    for (int ks = 0; ks < 2; ++ks) {
      bf16x8 af[4], bfv[4];
#pragma unroll
      for (int fm = 0; fm < 4; ++fm)
        af[fm] = *(const bf16x8*)(As + (wm * 64 + fm * 16 + (l & 15)) * 64 + ks * 32 + (l >> 4) * 8);
#pragma unroll
      for (int fn = 0; fn < 4; ++fn)
        bfv[fn] = *(const bf16x8*)(Bs + (wn * 64 + fn * 16 + (l & 15)) * 64 + ks * 32 + (l >> 4) * 8);
#pragma unroll
      for (int fm = 0; fm < 4; ++fm)
#pragma unroll
        for (int fn = 0; fn < 4; ++fn)
          acc[fm][fn] = __builtin_amdgcn_mfma_f32_16x16x32_bf16(af[fm], bfv[fn], acc[fm][fn], 0, 0, 0);
    }
    __syncthreads();
  }
  float bev[4];
#pragma unroll
  for (int fn = 0; fn < 4; ++fn)
    bev[fn] = be[e * H_DIM + nh * 128 + wn * 64 + fn * 16 + (l & 15)];
#pragma unroll
  for (int fm = 0; fm < 4; ++fm) {
#pragma unroll
    for (int fn = 0; fn < 4; ++fn) {
      int col = nh * 128 + wn * 64 + fn * 16 + (l & 15);
#pragma unroll
      for (int j = 0; j < 4; ++j) {
        int row = m0 + wm * 64 + fm * 16 + (l >> 4) * 4 + j;
        float vv = fmaxf(acc[fm][fn][j] + bev[fn], 0.f);
        E[(size_t)row * (N_EXP * H_DIM) + e * H_DIM + col] = f2bf(vv);
      }
    }
  }
}

// ---------------------------------------------------------------------------
// Kernel 4: combine. towers[t][b][h] = sum_e G[b][t][e] * E[b][e][h]
// one wave per row, lanes cover h (4 each), float4 I/O.
// ---------------------------------------------------------------------------
__global__ void k_combine(const unsigned short* __restrict__ E, const float* __restrict__ G,
                          float* __restrict__ out) {
  int t = threadIdx.x;
  int wv = t >> 6, l = t & 63;
  int r = blockIdx.x * 4 + wv;
  const unsigned short* er = E + (size_t)r * (N_EXP * H_DIM);
  const float* g = G + (size_t)r * 32;
  float acc[4][4];
#pragma unroll
  for (int i = 0; i < 4; ++i)
#pragma unroll
    for (int j = 0; j < 4; ++j) acc[i][j] = 0.f;
#pragma unroll
  for (int e = 0; e < 8; ++e) {
    ushort4 u = *(const ushort4*)(er + e * H_DIM + l * 4);
    float f0 = bf2f(u.x), f1 = bf2f(u.y), f2 = bf2f(u.z), f3 = bf2f(u.w);
#pragma unroll
    for (int tk = 0; tk < 4; ++tk) {
      float gv = g[tk * 8 + e];
      acc[tk][0] += gv * f0;
      acc[tk][1] += gv * f1;
      acc[tk][2] += gv * f2;
      acc[tk][3] += gv * f3;
    }
  }
#pragma unroll
  for (int tk = 0; tk < 4; ++tk) {
    float4 o = make_float4(acc[tk][0], acc[tk][1], acc[tk][2], acc[tk][3]);
    *(float4*)(out + ((size_t)tk * B_ROWS + r) * H_DIM + l * 4) = o;
  }
}

extern "C" void kernel_launch(void* const* d_in, const int* in_sizes, int n_in,
                              void* d_out, int out_size, void* d_ws, size_t ws_size,
                              hipStream_t stream) {
  const float* x  = (const float*)d_in[0];
  const float* We = (const float*)d_in[1];
  const float* be = (const float*)d_in[2];
  const float* Wg = (const float*)d_in[3];
  const float* bg = (const float*)d_in[4];
  float* out = (float*)d_out;
  char* ws = (char*)d_ws;
  unsigned short* x_b  = (unsigned short*)(ws + WS_XB);
  unsigned short* We_t = (unsigned short*)(ws + WS_WET);
  unsigned short* Wg_t = (unsigned short*)(ws + WS_WGT);
  float*          G    = (float*)(ws + WS_G);
  unsigned short* E    = (unsigned short*)(ws + WS_E);

  k_prep_w<<<513, 256, 0, stream>>>(We, Wg, We_t, Wg_t);
  k_gates<<<B_ROWS / 64, 256, 0, stream>>>(x, Wg_t, bg, x_b, G);
  k_expert<<<(B_ROWS / 128) * N_EXP * 2, 256, 0, stream>>>(x_b, We_t, be, E);
  k_combine<<<B_ROWS / 4, 256, 0, stream>>>(E, G, out);
}

// Round 2
// 259.517 us; speedup vs baseline: 1.1072x; 1.1072x over previous
//
#include <hip/hip_runtime.h>

#define B_ROWS 16384
#define D_IN   1024
#define H_DIM  256
#define N_EXP  8
#define N_TASK 4

typedef short bf16x8 __attribute__((ext_vector_type(8)));
typedef float f32x4  __attribute__((ext_vector_type(4)));

static __device__ __forceinline__ unsigned short f2bf(float f) {
  unsigned int u = __float_as_uint(f);
  u += 0x7fffu + ((u >> 16) & 1u);   // RNE
  return (unsigned short)(u >> 16);
}
static __device__ __forceinline__ float bf2f(unsigned short u) {
  return __uint_as_float(((unsigned int)u) << 16);
}

// workspace layout (bytes)
#define WS_XB   0u          // ushort[16384*1024]  = 33,554,432 B
#define WS_WET  33554432u   // ushort[8*256*1024]  =  4,194,304 B
#define WS_WGT  37748736u   // ushort[32*1024]     =     65,536 B
#define WS_G    37814272u   // float [16384*32]    =  2,097,152 B
#define WS_E    39911424u   // ushort[16384*2048]  = 67,108,864 B
// Gp (gate partials, 4*16384*32 fp32 = 8 MB) overlays WS_E: fully consumed by
// k_gfin before k_expert writes E.

// ---------------------------------------------------------------------------
// Kernel 1: cast+transpose We -> We_t[e][h][k] bf16 ; Wg -> Wg_t[n][k] bf16
// ---------------------------------------------------------------------------
__global__ void k_prep_w(const float* __restrict__ We, const float* __restrict__ Wg,
                         unsigned short* __restrict__ We_t, unsigned short* __restrict__ Wg_t) {
  int bid = blockIdx.x;
  int t = threadIdx.x;
  if (bid < 512) {
    // one 64x64 tile of We[e]: [k][h] -> [h][k]
    int e = bid >> 6;
    int tl = bid & 63;
    int k0 = (tl >> 2) * 64, h0 = (tl & 3) * 64;
    __shared__ unsigned short tile[64][72];   // [h][k], padded
    const float* src = We + (size_t)e * (D_IN * H_DIM);
#pragma unroll
    for (int i = 0; i < 4; ++i) {
      int kk = (t >> 4) + i * 16;
      int hh = (t & 15) * 4;
      float4 v = *(const float4*)(src + (size_t)(k0 + kk) * H_DIM + h0 + hh);
      tile[hh + 0][kk] = f2bf(v.x);
      tile[hh + 1][kk] = f2bf(v.y);
      tile[hh + 2][kk] = f2bf(v.z);
      tile[hh + 3][kk] = f2bf(v.w);
    }
    __syncthreads();
    unsigned short* dst = We_t + (size_t)e * (H_DIM * D_IN);
#pragma unroll
    for (int i = 0; i < 4; ++i) {
      int hh = (t >> 4) + i * 16;
      int kk = (t & 15) * 4;
      ushort4 u = *(const ushort4*)&tile[hh][kk];
      *(ushort4*)(dst + (size_t)(h0 + hh) * D_IN + k0 + kk) = u;
    }
  } else {
    // Wg[4][1024][8] -> Wg_t[n=t*8+e][k]
    int n = t & 31;
    int kbase = (t >> 5) * 128;
    int tsk = n >> 3, e = n & 7;
    for (int i = 0; i < 128; ++i) {
      int k = kbase + i;
      Wg_t[(size_t)n * D_IN + k] = f2bf(Wg[(size_t)tsk * (D_IN * 8) + (size_t)k * 8 + e]);
    }
  }
}

// ---------------------------------------------------------------------------
// Kernel 2: streaming cast x (fp32) -> x_b (bf16)
// ---------------------------------------------------------------------------
__global__ void k_cast(const float* __restrict__ x, unsigned short* __restrict__ x_b) {
  size_t n = (size_t)B_ROWS * D_IN;
  size_t i = ((size_t)blockIdx.x * blockDim.x + threadIdx.x) * 4;
  size_t stride = (size_t)gridDim.x * blockDim.x * 4;
  for (; i < n; i += stride) {
    float4 v = *(const float4*)(x + i);
    ushort4 u;
    u.x = f2bf(v.x); u.y = f2bf(v.y); u.z = f2bf(v.z); u.w = f2bf(v.w);
    *(ushort4*)(x_b + i) = u;
  }
}

// ---------------------------------------------------------------------------
// Kernel 3: gate logit partials, K-split. grid (256 m-tiles, 4 k-splits).
// Each block: 64 rows x 32 gates over k-range of 256. Partials -> Gp.
// ---------------------------------------------------------------------------
__global__ void k_gates(const unsigned short* __restrict__ x_b,
                        const unsigned short* __restrict__ Wg_t,
                        float* __restrict__ Gp) {
  __shared__ unsigned short xs[64][136];
  __shared__ unsigned short wgs[32][136];
  int m0 = blockIdx.x * 64;
  int ks = blockIdx.y;
  int kbase = ks * 256;
  int t = threadIdx.x;
  int wv = t >> 6, l = t & 63;
  f32x4 acc0 = {0.f, 0.f, 0.f, 0.f}, acc1 = {0.f, 0.f, 0.f, 0.f};

  for (int k0 = kbase; k0 < kbase + 256; k0 += 128) {
    {
      int r = t >> 2, c = (t & 3) * 32;
      const unsigned short* p = x_b + (size_t)(m0 + r) * D_IN + k0 + c;
#pragma unroll
      for (int i = 0; i < 8; ++i)
        *(ushort4*)&xs[r][c + i * 4] = *(const ushort4*)(p + i * 4);
    }
    {
      int n = t >> 3;
      int kk = (t & 7) * 16;
      const unsigned short* p = Wg_t + (size_t)n * D_IN + k0 + kk;
#pragma unroll
      for (int i = 0; i < 4; ++i)
        *(ushort4*)&wgs[n][kk + i * 4] = *(const ushort4*)(p + i * 4);
    }
    __syncthreads();
#pragma unroll
    for (int kk = 0; kk < 4; ++kk) {
      bf16x8 a  = *(const bf16x8*)&xs[wv * 16 + (l & 15)][kk * 32 + (l >> 4) * 8];
      bf16x8 b0 = *(const bf16x8*)&wgs[(l & 15)][kk * 32 + (l >> 4) * 8];
      bf16x8 b1 = *(const bf16x8*)&wgs[16 + (l & 15)][kk * 32 + (l >> 4) * 8];
      acc0 = __builtin_amdgcn_mfma_f32_16x16x32_bf16(a, b0, acc0, 0, 0, 0);
      acc1 = __builtin_amdgcn_mfma_f32_16x16x32_bf16(a, b1, acc1, 0, 0, 0);
    }
    __syncthreads();
  }
  float* Gq = Gp + (size_t)ks * (B_ROWS * 32);
  int rbase = m0 + wv * 16 + (l >> 4) * 4;
  int col = l & 15;
#pragma unroll
  for (int j = 0; j < 4; ++j) {
    Gq[(size_t)(rbase + j) * 32 + col]      = acc0[j];
    Gq[(size_t)(rbase + j) * 32 + 16 + col] = acc1[j];
  }
}

// ---------------------------------------------------------------------------
// Kernel 4: finalize gates: sum 4 partials + bg, softmax per task -> G
// ---------------------------------------------------------------------------
__global__ void k_gfin(const float* __restrict__ Gp, const float* __restrict__ bg,
                       float* __restrict__ G) {
  int row = blockIdx.x * 256 + threadIdx.x;
  float v[32];
#pragma unroll
  for (int c = 0; c < 8; ++c) {
    float4 a = *(const float4*)(Gp + (size_t)row * 32 + c * 4);
#pragma unroll
    for (int ks = 1; ks < 4; ++ks) {
      float4 b = *(const float4*)(Gp + (size_t)ks * (B_ROWS * 32) + (size_t)row * 32 + c * 4);
      a.x += b.x; a.y += b.y; a.z += b.z; a.w += b.w;
    }
    v[c * 4 + 0] = a.x; v[c * 4 + 1] = a.y; v[c * 4 + 2] = a.z; v[c * 4 + 3] = a.w;
  }
#pragma unroll
  for (int n = 0; n < 32; ++n) v[n] += bg[n];
#pragma unroll
  for (int tk = 0; tk < 4; ++tk) {
    float mx = -1e30f;
#pragma unroll
    for (int e = 0; e < 8; ++e) mx = fmaxf(mx, v[tk * 8 + e]);
    float s = 0.f;
#pragma unroll
    for (int e = 0; e < 8; ++e) { v[tk * 8 + e] = __expf(v[tk * 8 + e] - mx); s += v[tk * 8 + e]; }
    float inv = 1.f / s;
#pragma unroll
    for (int e = 0; e < 8; ++e) v[tk * 8 + e] *= inv;
  }
#pragma unroll
  for (int c = 0; c < 8; ++c)
    *(float4*)(G + (size_t)row * 32 + c * 4) =
        make_float4(v[c * 4], v[c * 4 + 1], v[c * 4 + 2], v[c * 4 + 3]);
}

// ---------------------------------------------------------------------------
// Kernel 5: expert GEMM, m97 structure + XOR-swizzled LDS + XCD block swizzle.
// block 256 thr = 4 waves, each wave 64x64 (4x4 frags of 16x16x32 bf16).
// E[b][e*256+h] = relu(x@We + be) -> bf16 ws
// ---------------------------------------------------------------------------
__global__ __launch_bounds__(256) void k_expert(const unsigned short* __restrict__ x_b,
                                                const unsigned short* __restrict__ We_t,
                                                const float* __restrict__ be,
                                                unsigned short* __restrict__ E) {
  __shared__ unsigned short As[128 * 64];
  __shared__ unsigned short Bs[128 * 64];
  // XCD swizzle: all 16 (e,nh) blocks of one m-tile share bid%8 -> same XCD L2
  int bid = blockIdx.x;
  int xcd = bid & 7;
  int jj  = bid >> 3;          // 0..255
  int enh = jj & 15;
  int mlo = jj >> 4;           // 0..15
  int m   = mlo * 8 + xcd;     // 0..127
  int e   = enh >> 1;
  int nh  = enh & 1;
  int m0 = m * 128;
  int t = threadIdx.x;
  int wv = t >> 6, l = t & 63;
  int wm = wv >> 1, wn = wv & 1;

  const unsigned short* Ab = x_b + (size_t)m0 * D_IN;
  const unsigned short* Bb = We_t + (size_t)e * (H_DIM * D_IN) + (size_t)(nh * 128) * D_IN;

  f32x4 acc[4][4];
#pragma unroll
  for (int i = 0; i < 4; ++i)
#pragma unroll
    for (int j = 0; j < 4; ++j) acc[i][j] = (f32x4){0.f, 0.f, 0.f, 0.f};

  int rr = t >> 3;                              // 0..31 : row within 32-row chunk
  int ccs = (((t & 7) ^ (rr & 7)) * 8);         // XOR-swizzled source k-granule
  int lq = l >> 4;                              // 0..3
  int lr = l & 15;
  int lx = l & 7;                               // = row&7 for fragment rows
  for (int k0 = 0; k0 < D_IN; k0 += 64) {
#pragma unroll
    for (int i = 0; i < 4; ++i) {
      __builtin_amdgcn_global_load_lds(
          (const __attribute__((address_space(1))) void*)(Ab + (size_t)(rr + i * 32) * D_IN + k0 + ccs),
          (__attribute__((address_space(3))) void*)(As + i * 2048 + t * 8),
          16, 0, 0);
    }
#pragma unroll
    for (int i = 0; i < 4; ++i) {
      __builtin_amdgcn_global_load_lds(
          (const __attribute__((address_space(1))) void*)(Bb + (size_t)(rr + i * 32) * D_IN + k0 + ccs),
          (__attribute__((address_space(3))) void*)(Bs + i * 2048 + t * 8),
          16, 0, 0);
    }
    __syncthreads();
#pragma unroll
    for (int ks = 0; ks < 2; ++ks) {
      int gsw = ((ks * 4 + lq) ^ lx) * 8;       // swizzled granule offset (ushorts)
      bf16x8 af[4], bfv[4];
#pragma unroll
      for (int fm = 0; fm < 4; ++fm)
        af[fm] = *(const bf16x8*)(As + (wm * 64 + fm * 16 + lr) * 64 + gsw);
#pragma unroll
      for (int fn = 0; fn < 4; ++fn)
        bfv[fn] = *(const bf16x8*)(Bs + (wn * 64 + fn * 16 + lr) * 64 + gsw);
#pragma unroll
      for (int fm = 0; fm < 4; ++fm)
#pragma unroll
        for (int fn = 0; fn < 4; ++fn)
          acc[fm][fn] = __builtin_amdgcn_mfma_f32_16x16x32_bf16(af[fm], bfv[fn], acc[fm][fn], 0, 0, 0);
    }
    __syncthreads();
  }
  float bev[4];
#pragma unroll
  for (int fn = 0; fn < 4; ++fn)
    bev[fn] = be[e * H_DIM + nh * 128 + wn * 64 + fn * 16 + lr];
#pragma unroll
  for (int fm = 0; fm < 4; ++fm) {
#pragma unroll
    for (int fn = 0; fn < 4; ++fn) {
      int col = nh * 128 + wn * 64 + fn * 16 + lr;
#pragma unroll
      for (int j = 0; j < 4; ++j) {
        int row = m0 + wm * 64 + fm * 16 + lq * 4 + j;
        float vv = fmaxf(acc[fm][fn][j] + bev[fn], 0.f);
        E[(size_t)row * (N_EXP * H_DIM) + e * H_DIM + col] = f2bf(vv);
      }
    }
  }
}

// ---------------------------------------------------------------------------
// Kernel 6: combine. towers[t][b][h] = sum_e G[b][t][e] * E[b][e][h]
// one wave per row, lanes cover h (4 each), float4 I/O.
// ---------------------------------------------------------------------------
__global__ void k_combine(const unsigned short* __restrict__ E, const float* __restrict__ G,
                          float* __restrict__ out) {
  int t = threadIdx.x;
  int wv = t >> 6, l = t & 63;
  int r = blockIdx.x * 4 + wv;
  const unsigned short* er = E + (size_t)r * (N_EXP * H_DIM);
  const float* g = G + (size_t)r * 32;
  float acc[4][4];
#pragma unroll
  for (int i = 0; i < 4; ++i)
#pragma unroll
    for (int j = 0; j < 4; ++j) acc[i][j] = 0.f;
#pragma unroll
  for (int e = 0; e < 8; ++e) {
    ushort4 u = *(const ushort4*)(er + e * H_DIM + l * 4);
    float f0 = bf2f(u.x), f1 = bf2f(u.y), f2 = bf2f(u.z), f3 = bf2f(u.w);
#pragma unroll
    for (int tk = 0; tk < 4; ++tk) {
      float gv = g[tk * 8 + e];
      acc[tk][0] += gv * f0;
      acc[tk][1] += gv * f1;
      acc[tk][2] += gv * f2;
      acc[tk][3] += gv * f3;
    }
  }
#pragma unroll
  for (int tk = 0; tk < 4; ++tk) {
    float4 o = make_float4(acc[tk][0], acc[tk][1], acc[tk][2], acc[tk][3]);
    *(float4*)(out + ((size_t)tk * B_ROWS + r) * H_DIM + l * 4) = o;
  }
}

extern "C" void kernel_launch(void* const* d_in, const int* in_sizes, int n_in,
                              void* d_out, int out_size, void* d_ws, size_t ws_size,
                              hipStream_t stream) {
  const float* x  = (const float*)d_in[0];
  const float* We = (const float*)d_in[1];
  const float* be = (const float*)d_in[2];
  const float* Wg = (const float*)d_in[3];
  const float* bg = (const float*)d_in[4];
  float* out = (float*)d_out;
  char* ws = (char*)d_ws;
  unsigned short* x_b  = (unsigned short*)(ws + WS_XB);
  unsigned short* We_t = (unsigned short*)(ws + WS_WET);
  unsigned short* Wg_t = (unsigned short*)(ws + WS_WGT);
  float*          G    = (float*)(ws + WS_G);
  unsigned short* E    = (unsigned short*)(ws + WS_E);
  float*          Gp   = (float*)(ws + WS_E);   // overlays E; consumed before k_expert

  k_prep_w<<<513, 256, 0, stream>>>(We, Wg, We_t, Wg_t);
  k_cast<<<4096, 256, 0, stream>>>(x, x_b);
  k_gates<<<dim3(B_ROWS / 64, 4), 256, 0, stream>>>(x_b, Wg_t, Gp);
  k_gfin<<<B_ROWS / 256, 256, 0, stream>>>(Gp, bg, G);
  k_expert<<<(B_ROWS / 128) * N_EXP * 2, 256, 0, stream>>>(x_b, We_t, be, E);
  k_combine<<<B_ROWS / 4, 256, 0, stream>>>(E, G, out);
}

// Round 3
// 256.798 us; speedup vs baseline: 1.1189x; 1.0106x over previous
//
#include <hip/hip_runtime.h>

#define B_ROWS 16384
#define D_IN   1024
#define H_DIM  256
#define N_EXP  8
#define N_TASK 4

typedef short bf16x8 __attribute__((ext_vector_type(8)));
typedef float f32x4  __attribute__((ext_vector_type(4)));
typedef float f32x16 __attribute__((ext_vector_type(16)));

static __device__ __forceinline__ unsigned short f2bf(float f) {
  unsigned int u = __float_as_uint(f);
  u += 0x7fffu + ((u >> 16) & 1u);   // RNE
  return (unsigned short)(u >> 16);
}
static __device__ __forceinline__ float bf2f(unsigned short u) {
  return __uint_as_float(((unsigned int)u) << 16);
}

// workspace layout (bytes)
#define WS_XB   0u          // ushort[16384*1024]  = 33,554,432 B
#define WS_WET  33554432u   // ushort[8*256*1024]  =  4,194,304 B
#define WS_WGT  37748736u   // ushort[32*1024]     =     65,536 B
#define WS_G    37814272u   // float [16384*32]    =  2,097,152 B
#define WS_E    39911424u   // ushort[16384*2048]  = 67,108,864 B
// Gp (gate partials, 4*16384*32 fp32 = 8 MB) overlays WS_E: fully consumed by
// k_gfin before k_expert writes E.

// ---------------------------------------------------------------------------
// Kernel 1: cast+transpose We -> We_t[e][h][k] bf16 ; Wg -> Wg_t[n][k] bf16
// ---------------------------------------------------------------------------
__global__ void k_prep_w(const float* __restrict__ We, const float* __restrict__ Wg,
                         unsigned short* __restrict__ We_t, unsigned short* __restrict__ Wg_t) {
  int bid = blockIdx.x;
  int t = threadIdx.x;
  if (bid < 512) {
    // one 64x64 tile of We[e]: [k][h] -> [h][k]
    int e = bid >> 6;
    int tl = bid & 63;
    int k0 = (tl >> 2) * 64, h0 = (tl & 3) * 64;
    __shared__ unsigned short tile[64][72];   // [h][k], padded
    const float* src = We + (size_t)e * (D_IN * H_DIM);
#pragma unroll
    for (int i = 0; i < 4; ++i) {
      int kk = (t >> 4) + i * 16;
      int hh = (t & 15) * 4;
      float4 v = *(const float4*)(src + (size_t)(k0 + kk) * H_DIM + h0 + hh);
      tile[hh + 0][kk] = f2bf(v.x);
      tile[hh + 1][kk] = f2bf(v.y);
      tile[hh + 2][kk] = f2bf(v.z);
      tile[hh + 3][kk] = f2bf(v.w);
    }
    __syncthreads();
    unsigned short* dst = We_t + (size_t)e * (H_DIM * D_IN);
#pragma unroll
    for (int i = 0; i < 4; ++i) {
      int hh = (t >> 4) + i * 16;
      int kk = (t & 15) * 4;
      ushort4 u = *(const ushort4*)&tile[hh][kk];
      *(ushort4*)(dst + (size_t)(h0 + hh) * D_IN + k0 + kk) = u;
    }
  } else {
    // Wg[4][1024][8] -> Wg_t[n=t*8+e][k]
    int n = t & 31;
    int kbase = (t >> 5) * 128;
    int tsk = n >> 3, e = n & 7;
    for (int i = 0; i < 128; ++i) {
      int k = kbase + i;
      Wg_t[(size_t)n * D_IN + k] = f2bf(Wg[(size_t)tsk * (D_IN * 8) + (size_t)k * 8 + e]);
    }
  }
}

// ---------------------------------------------------------------------------
// Kernel 2: fused cast + gate logit partials, K-split.
// grid (256 m-tiles, 4 k-splits). Each block owns a DISJOINT slice of x:
// rows m0..m0+63, k in [ks*256, ks*256+256): reads x fp32, casts -> x_b,
// MFMAs 64x32 logit partials -> Gp.
// ---------------------------------------------------------------------------
__global__ void k_gates(const float* __restrict__ x,
                        const unsigned short* __restrict__ Wg_t,
                        unsigned short* __restrict__ x_b,
                        float* __restrict__ Gp) {
  __shared__ unsigned short xs[64][136];
  __shared__ unsigned short wgs[32][136];
  int m0 = blockIdx.x * 64;
  int ks = blockIdx.y;
  int kbase = ks * 256;
  int t = threadIdx.x;
  int wv = t >> 6, l = t & 63;
  f32x4 acc0 = {0.f, 0.f, 0.f, 0.f}, acc1 = {0.f, 0.f, 0.f, 0.f};

  for (int k0 = kbase; k0 < kbase + 256; k0 += 128) {
    {
      int r = t >> 2;
      int cb = (t & 3) * 32;
      const float* p = x + (size_t)(m0 + r) * D_IN + k0 + cb;
      unsigned short* q = x_b + (size_t)(m0 + r) * D_IN + k0 + cb;
#pragma unroll
      for (int i = 0; i < 8; ++i) {
        float4 v = *(const float4*)(p + i * 4);
        ushort4 u;
        u.x = f2bf(v.x); u.y = f2bf(v.y); u.z = f2bf(v.z); u.w = f2bf(v.w);
        *(ushort4*)&xs[r][cb + i * 4] = u;
        *(ushort4*)(q + i * 4) = u;
      }
    }
    {
      int n = t >> 3;
      int kk = (t & 7) * 16;
      const unsigned short* p = Wg_t + (size_t)n * D_IN + k0 + kk;
#pragma unroll
      for (int i = 0; i < 4; ++i)
        *(ushort4*)&wgs[n][kk + i * 4] = *(const ushort4*)(p + i * 4);
    }
    __syncthreads();
#pragma unroll
    for (int kk = 0; kk < 4; ++kk) {
      bf16x8 a  = *(const bf16x8*)&xs[wv * 16 + (l & 15)][kk * 32 + (l >> 4) * 8];
      bf16x8 b0 = *(const bf16x8*)&wgs[(l & 15)][kk * 32 + (l >> 4) * 8];
      bf16x8 b1 = *(const bf16x8*)&wgs[16 + (l & 15)][kk * 32 + (l >> 4) * 8];
      acc0 = __builtin_amdgcn_mfma_f32_16x16x32_bf16(a, b0, acc0, 0, 0, 0);
      acc1 = __builtin_amdgcn_mfma_f32_16x16x32_bf16(a, b1, acc1, 0, 0, 0);
    }
    __syncthreads();
  }
  float* Gq = Gp + (size_t)ks * (B_ROWS * 32);
  int rbase = m0 + wv * 16 + (l >> 4) * 4;
  int col = l & 15;
#pragma unroll
  for (int j = 0; j < 4; ++j) {
    Gq[(size_t)(rbase + j) * 32 + col]      = acc0[j];
    Gq[(size_t)(rbase + j) * 32 + 16 + col] = acc1[j];
  }
}

// ---------------------------------------------------------------------------
// Kernel 3: finalize gates: sum 4 partials + bg, softmax per task -> G
// ---------------------------------------------------------------------------
__global__ void k_gfin(const float* __restrict__ Gp, const float* __restrict__ bg,
                       float* __restrict__ G) {
  int row = blockIdx.x * 256 + threadIdx.x;
  float v[32];
#pragma unroll
  for (int c = 0; c < 8; ++c) {
    float4 a = *(const float4*)(Gp + (size_t)row * 32 + c * 4);
#pragma unroll
    for (int ks = 1; ks < 4; ++ks) {
      float4 b = *(const float4*)(Gp + (size_t)ks * (B_ROWS * 32) + (size_t)row * 32 + c * 4);
      a.x += b.x; a.y += b.y; a.z += b.z; a.w += b.w;
    }
    v[c * 4 + 0] = a.x; v[c * 4 + 1] = a.y; v[c * 4 + 2] = a.z; v[c * 4 + 3] = a.w;
  }
#pragma unroll
  for (int n = 0; n < 32; ++n) v[n] += bg[n];
#pragma unroll
  for (int tk = 0; tk < 4; ++tk) {
    float mx = -1e30f;
#pragma unroll
    for (int e = 0; e < 8; ++e) mx = fmaxf(mx, v[tk * 8 + e]);
    float s = 0.f;
#pragma unroll
    for (int e = 0; e < 8; ++e) { v[tk * 8 + e] = __expf(v[tk * 8 + e] - mx); s += v[tk * 8 + e]; }
    float inv = 1.f / s;
#pragma unroll
    for (int e = 0; e < 8; ++e) v[tk * 8 + e] *= inv;
  }
#pragma unroll
  for (int c = 0; c < 8; ++c)
    *(float4*)(G + (size_t)row * 32 + c * 4) =
        make_float4(v[c * 4], v[c * 4 + 1], v[c * 4 + 2], v[c * 4 + 3]);
}

// ---------------------------------------------------------------------------
// Kernel 4: expert GEMM, 32x32x16 MFMA. block 256 thr = 4 waves (2x2),
// wave 64x64 = 2x2 frags of 32x32. XOR-swizzled LDS, XCD block swizzle.
// E[b][e*256+h] = relu(x@We + be) -> bf16 ws
// A frag: A[m=l&31][k=(l>>5)*8+j]; C/D: col=l&31, row=(reg&3)+8*(reg>>2)+4*(l>>5)
// ---------------------------------------------------------------------------
__global__ __launch_bounds__(256) void k_expert(const unsigned short* __restrict__ x_b,
                                                const unsigned short* __restrict__ We_t,
                                                const float* __restrict__ be,
                                                unsigned short* __restrict__ E) {
  __shared__ unsigned short As[128 * 64];
  __shared__ unsigned short Bs[128 * 64];
  // XCD swizzle: all 16 (e,nh) blocks of one m-tile share bid%8 -> same XCD L2
  int bid = blockIdx.x;
  int xcd = bid & 7;
  int jj  = bid >> 3;          // 0..255
  int enh = jj & 15;
  int mlo = jj >> 4;           // 0..15
  int m   = mlo * 8 + xcd;     // 0..127
  int e   = enh >> 1;
  int nh  = enh & 1;
  int m0 = m * 128;
  int t = threadIdx.x;
  int wv = t >> 6, l = t & 63;
  int wm = wv >> 1, wn = wv & 1;
  int ln = l & 31, lh = l >> 5;

  const unsigned short* Ab = x_b + (size_t)m0 * D_IN;
  const unsigned short* Bb = We_t + (size_t)e * (H_DIM * D_IN) + (size_t)(nh * 128) * D_IN;

  f32x16 acc[2][2];
#pragma unroll
  for (int i = 0; i < 2; ++i)
#pragma unroll
    for (int j = 0; j < 2; ++j)
#pragma unroll
      for (int r = 0; r < 16; ++r) acc[i][j][r] = 0.f;

  int rr = t >> 3;                              // 0..31 : row within 32-row chunk
  int ccs = (((t & 7) ^ (rr & 7)) * 8);         // XOR-swizzled source k-granule
  for (int k0 = 0; k0 < D_IN; k0 += 64) {
#pragma unroll
    for (int i = 0; i < 4; ++i) {
      __builtin_amdgcn_global_load_lds(
          (const __attribute__((address_space(1))) void*)(Ab + (size_t)(rr + i * 32) * D_IN + k0 + ccs),
          (__attribute__((address_space(3))) void*)(As + i * 2048 + t * 8),
          16, 0, 0);
    }
#pragma unroll
    for (int i = 0; i < 4; ++i) {
      __builtin_amdgcn_global_load_lds(
          (const __attribute__((address_space(1))) void*)(Bb + (size_t)(rr + i * 32) * D_IN + k0 + ccs),
          (__attribute__((address_space(3))) void*)(Bs + i * 2048 + t * 8),
          16, 0, 0);
    }
    __syncthreads();
#pragma unroll
    for (int step = 0; step < 4; ++step) {
      int gsw = ((step * 2 + lh) ^ (l & 7)) * 8;   // swizzled granule (ushorts)
      bf16x8 af[2], bfv[2];
#pragma unroll
      for (int fm = 0; fm < 2; ++fm)
        af[fm] = *(const bf16x8*)(As + (wm * 64 + fm * 32 + ln) * 64 + gsw);
#pragma unroll
      for (int fn = 0; fn < 2; ++fn)
        bfv[fn] = *(const bf16x8*)(Bs + (wn * 64 + fn * 32 + ln) * 64 + gsw);
#pragma unroll
      for (int fm = 0; fm < 2; ++fm)
#pragma unroll
        for (int fn = 0; fn < 2; ++fn)
          acc[fm][fn] = __builtin_amdgcn_mfma_f32_32x32x16_bf16(af[fm], bfv[fn], acc[fm][fn], 0, 0, 0);
    }
    __syncthreads();
  }
  float bev[2];
#pragma unroll
  for (int fn = 0; fn < 2; ++fn)
    bev[fn] = be[e * H_DIM + nh * 128 + wn * 64 + fn * 32 + ln];
#pragma unroll
  for (int fm = 0; fm < 2; ++fm) {
#pragma unroll
    for (int fn = 0; fn < 2; ++fn) {
      int col = nh * 128 + wn * 64 + fn * 32 + ln;
#pragma unroll
      for (int reg = 0; reg < 16; ++reg) {
        int row = m0 + wm * 64 + fm * 32 + (reg & 3) + 8 * (reg >> 2) + 4 * lh;
        float vv = fmaxf(acc[fm][fn][reg] + bev[fn], 0.f);
        E[(size_t)row * (N_EXP * H_DIM) + e * H_DIM + col] = f2bf(vv);
      }
    }
  }
}

// ---------------------------------------------------------------------------
// Kernel 5: combine. towers[t][b][h] = sum_e G[b][t][e] * E[b][e][h]
// one wave per row, lanes cover h (4 each), float4 I/O.
// ---------------------------------------------------------------------------
__global__ void k_combine(const unsigned short* __restrict__ E, const float* __restrict__ G,
                          float* __restrict__ out) {
  int t = threadIdx.x;
  int wv = t >> 6, l = t & 63;
  int r = blockIdx.x * 4 + wv;
  const unsigned short* er = E + (size_t)r * (N_EXP * H_DIM);
  const float* g = G + (size_t)r * 32;
  float acc[4][4];
#pragma unroll
  for (int i = 0; i < 4; ++i)
#pragma unroll
    for (int j = 0; j < 4; ++j) acc[i][j] = 0.f;
#pragma unroll
  for (int e = 0; e < 8; ++e) {
    ushort4 u = *(const ushort4*)(er + e * H_DIM + l * 4);
    float f0 = bf2f(u.x), f1 = bf2f(u.y), f2 = bf2f(u.z), f3 = bf2f(u.w);
#pragma unroll
    for (int tk = 0; tk < 4; ++tk) {
      float gv = g[tk * 8 + e];
      acc[tk][0] += gv * f0;
      acc[tk][1] += gv * f1;
      acc[tk][2] += gv * f2;
      acc[tk][3] += gv * f3;
    }
  }
#pragma unroll
  for (int tk = 0; tk < 4; ++tk) {
    float4 o = make_float4(acc[tk][0], acc[tk][1], acc[tk][2], acc[tk][3]);
    *(float4*)(out + ((size_t)tk * B_ROWS + r) * H_DIM + l * 4) = o;
  }
}

extern "C" void kernel_launch(void* const* d_in, const int* in_sizes, int n_in,
                              void* d_out, int out_size, void* d_ws, size_t ws_size,
                              hipStream_t stream) {
  const float* x  = (const float*)d_in[0];
  const float* We = (const float*)d_in[1];
  const float* be = (const float*)d_in[2];
  const float* Wg = (const float*)d_in[3];
  const float* bg = (const float*)d_in[4];
  float* out = (float*)d_out;
  char* ws = (char*)d_ws;
  unsigned short* x_b  = (unsigned short*)(ws + WS_XB);
  unsigned short* We_t = (unsigned short*)(ws + WS_WET);
  unsigned short* Wg_t = (unsigned short*)(ws + WS_WGT);
  float*          G    = (float*)(ws + WS_G);
  unsigned short* E    = (unsigned short*)(ws + WS_E);
  float*          Gp   = (float*)(ws + WS_E);   // overlays E; consumed before k_expert

  k_prep_w<<<513, 256, 0, stream>>>(We, Wg, We_t, Wg_t);
  k_gates<<<dim3(B_ROWS / 64, 4), 256, 0, stream>>>(x, Wg_t, x_b, Gp);
  k_gfin<<<B_ROWS / 256, 256, 0, stream>>>(Gp, bg, G);
  k_expert<<<(B_ROWS / 128) * N_EXP * 2, 256, 0, stream>>>(x_b, We_t, be, E);
  k_combine<<<B_ROWS / 4, 256, 0, stream>>>(E, G, out);
}

// Round 4
// 254.390 us; speedup vs baseline: 1.1295x; 1.0095x over previous
//
#include <hip/hip_runtime.h>

#define B_ROWS 16384
#define D_IN   1024
#define H_DIM  256
#define N_EXP  8
#define N_TASK 4

typedef short bf16x8 __attribute__((ext_vector_type(8)));
typedef float f32x4  __attribute__((ext_vector_type(4)));

static __device__ __forceinline__ unsigned short f2bf(float f) {
  unsigned int u = __float_as_uint(f);
  u += 0x7fffu + ((u >> 16) & 1u);   // RNE
  return (unsigned short)(u >> 16);
}
static __device__ __forceinline__ float bf2f(unsigned short u) {
  return __uint_as_float(((unsigned int)u) << 16);
}

// workspace layout (bytes)
#define WS_XB   0u          // ushort[16384*1024]  = 33,554,432 B
#define WS_WET  33554432u   // ushort[8*256*1024]  =  4,194,304 B
#define WS_WGT  37748736u   // ushort[32*1024]     =     65,536 B
#define WS_G    37814272u   // float [16384*32]    =  2,097,152 B (logits -> probs in place)
#define WS_E    39911424u   // ushort[16384*2048]  = 67,108,864 B

// ---------------------------------------------------------------------------
// Kernel 1: cast+transpose We -> We_t[e][h][k] bf16 ; Wg -> Wg_t[n][k] bf16
// ---------------------------------------------------------------------------
__global__ void k_prep_w(const float* __restrict__ We, const float* __restrict__ Wg,
                         unsigned short* __restrict__ We_t, unsigned short* __restrict__ Wg_t) {
  int bid = blockIdx.x;
  int t = threadIdx.x;
  if (bid < 512) {
    // one 64x64 tile of We[e]: [k][h] -> [h][k]
    int e = bid >> 6;
    int tl = bid & 63;
    int k0 = (tl >> 2) * 64, h0 = (tl & 3) * 64;
    __shared__ unsigned short tile[64][72];   // [h][k], padded
    const float* src = We + (size_t)e * (D_IN * H_DIM);
#pragma unroll
    for (int i = 0; i < 4; ++i) {
      int kk = (t >> 4) + i * 16;
      int hh = (t & 15) * 4;
      float4 v = *(const float4*)(src + (size_t)(k0 + kk) * H_DIM + h0 + hh);
      tile[hh + 0][kk] = f2bf(v.x);
      tile[hh + 1][kk] = f2bf(v.y);
      tile[hh + 2][kk] = f2bf(v.z);
      tile[hh + 3][kk] = f2bf(v.w);
    }
    __syncthreads();
    unsigned short* dst = We_t + (size_t)e * (H_DIM * D_IN);
#pragma unroll
    for (int i = 0; i < 4; ++i) {
      int hh = (t >> 4) + i * 16;
      int kk = (t & 15) * 4;
      ushort4 u = *(const ushort4*)&tile[hh][kk];
      *(ushort4*)(dst + (size_t)(h0 + hh) * D_IN + k0 + kk) = u;
    }
  } else {
    // Wg[4][1024][8] -> Wg_t[n=t*8+e][k]
    int n = t & 31;
    int kbase = (t >> 5) * 128;
    int tsk = n >> 3, e = n & 7;
    for (int i = 0; i < 128; ++i) {
      int k = kbase + i;
      Wg_t[(size_t)n * D_IN + k] = f2bf(Wg[(size_t)tsk * (D_IN * 8) + (size_t)k * 8 + e]);
    }
  }
}

// ---------------------------------------------------------------------------
// Kernel 2: fused cast + gate logit partials, K-split, atomic accumulate.
// grid (256 m-tiles, 4 k-splits). Each block owns a DISJOINT slice of x:
// rows m0..m0+63, k in [ks*256, ks*256+256): reads x fp32, casts -> x_b,
// MFMAs 64x32 logit partials, atomicAdd -> Glog (pre-zeroed).
// ---------------------------------------------------------------------------
__global__ void k_gates(const float* __restrict__ x,
                        const unsigned short* __restrict__ Wg_t,
                        unsigned short* __restrict__ x_b,
                        float* __restrict__ Glog) {
  __shared__ unsigned short xs[64][136];
  __shared__ unsigned short wgs[32][136];
  int m0 = blockIdx.x * 64;
  int ks = blockIdx.y;
  int kbase = ks * 256;
  int t = threadIdx.x;
  int wv = t >> 6, l = t & 63;
  f32x4 acc0 = {0.f, 0.f, 0.f, 0.f}, acc1 = {0.f, 0.f, 0.f, 0.f};

  for (int k0 = kbase; k0 < kbase + 256; k0 += 128) {
    {
      int r = t >> 2;
      int cb = (t & 3) * 32;
      const float* p = x + (size_t)(m0 + r) * D_IN + k0 + cb;
      unsigned short* q = x_b + (size_t)(m0 + r) * D_IN + k0 + cb;
#pragma unroll
      for (int i = 0; i < 8; ++i) {
        float4 v = *(const float4*)(p + i * 4);
        ushort4 u;
        u.x = f2bf(v.x); u.y = f2bf(v.y); u.z = f2bf(v.z); u.w = f2bf(v.w);
        *(ushort4*)&xs[r][cb + i * 4] = u;
        *(ushort4*)(q + i * 4) = u;
      }
    }
    {
      int n = t >> 3;
      int kk = (t & 7) * 16;
      const unsigned short* p = Wg_t + (size_t)n * D_IN + k0 + kk;
#pragma unroll
      for (int i = 0; i < 4; ++i)
        *(ushort4*)&wgs[n][kk + i * 4] = *(const ushort4*)(p + i * 4);
    }
    __syncthreads();
#pragma unroll
    for (int kk = 0; kk < 4; ++kk) {
      bf16x8 a  = *(const bf16x8*)&xs[wv * 16 + (l & 15)][kk * 32 + (l >> 4) * 8];
      bf16x8 b0 = *(const bf16x8*)&wgs[(l & 15)][kk * 32 + (l >> 4) * 8];
      bf16x8 b1 = *(const bf16x8*)&wgs[16 + (l & 15)][kk * 32 + (l >> 4) * 8];
      acc0 = __builtin_amdgcn_mfma_f32_16x16x32_bf16(a, b0, acc0, 0, 0, 0);
      acc1 = __builtin_amdgcn_mfma_f32_16x16x32_bf16(a, b1, acc1, 0, 0, 0);
    }
    __syncthreads();
  }
  int rbase = m0 + wv * 16 + (l >> 4) * 4;
  int col = l & 15;
#pragma unroll
  for (int j = 0; j < 4; ++j) {
    atomicAdd(&Glog[(size_t)(rbase + j) * 32 + col],      acc0[j]);
    atomicAdd(&Glog[(size_t)(rbase + j) * 32 + 16 + col], acc1[j]);
  }
}

// ---------------------------------------------------------------------------
// Kernel 3: expert GEMM (16x16x32 MFMA, m97 structure, XOR-swizzled LDS,
// XCD block swizzle) + gate softmax finalize in trailing blocks.
// blocks [0,2048): E[b][e*256+h] = relu(x@We + be) -> bf16 ws
// blocks [2048,2112): softmax(Glog+bg) in place -> G probs (disjoint memory)
// ---------------------------------------------------------------------------
__global__ __launch_bounds__(256) void k_expert(const unsigned short* __restrict__ x_b,
                                                const unsigned short* __restrict__ We_t,
                                                const float* __restrict__ be,
                                                const float* __restrict__ bg,
                                                float* __restrict__ Glog,
                                                unsigned short* __restrict__ E) {
  __shared__ unsigned short As[128 * 64];
  __shared__ unsigned short Bs[128 * 64];
  int bid = blockIdx.x;
  int t = threadIdx.x;

  if (bid >= 2048) {
    // ---- gate finalize: 64 blocks x 256 threads = 16384 rows ----
    int row = (bid - 2048) * 256 + t;
    float v[32];
#pragma unroll
    for (int c = 0; c < 8; ++c) {
      float4 a = *(const float4*)(Glog + (size_t)row * 32 + c * 4);
      v[c * 4 + 0] = a.x; v[c * 4 + 1] = a.y; v[c * 4 + 2] = a.z; v[c * 4 + 3] = a.w;
    }
#pragma unroll
    for (int n = 0; n < 32; ++n) v[n] += bg[n];
#pragma unroll
    for (int tk = 0; tk < 4; ++tk) {
      float mx = -1e30f;
#pragma unroll
      for (int e = 0; e < 8; ++e) mx = fmaxf(mx, v[tk * 8 + e]);
      float s = 0.f;
#pragma unroll
      for (int e = 0; e < 8; ++e) { v[tk * 8 + e] = __expf(v[tk * 8 + e] - mx); s += v[tk * 8 + e]; }
      float inv = 1.f / s;
#pragma unroll
      for (int e = 0; e < 8; ++e) v[tk * 8 + e] *= inv;
    }
#pragma unroll
    for (int c = 0; c < 8; ++c)
      *(float4*)(Glog + (size_t)row * 32 + c * 4) =
          make_float4(v[c * 4], v[c * 4 + 1], v[c * 4 + 2], v[c * 4 + 3]);
    return;
  }

  // ---- expert GEMM ----
  // XCD swizzle: all 16 (e,nh) blocks of one m-tile share bid%8 -> same XCD L2
  int xcd = bid & 7;
  int jj  = bid >> 3;          // 0..255
  int enh = jj & 15;
  int mlo = jj >> 4;           // 0..15
  int m   = mlo * 8 + xcd;     // 0..127
  int e   = enh >> 1;
  int nh  = enh & 1;
  int m0 = m * 128;
  int wv = t >> 6, l = t & 63;
  int wm = wv >> 1, wn = wv & 1;

  const unsigned short* Ab = x_b + (size_t)m0 * D_IN;
  const unsigned short* Bb = We_t + (size_t)e * (H_DIM * D_IN) + (size_t)(nh * 128) * D_IN;

  f32x4 acc[4][4];
#pragma unroll
  for (int i = 0; i < 4; ++i)
#pragma unroll
    for (int j = 0; j < 4; ++j) acc[i][j] = (f32x4){0.f, 0.f, 0.f, 0.f};

  int rr = t >> 3;                              // 0..31 : row within 32-row chunk
  int ccs = (((t & 7) ^ (rr & 7)) * 8);         // XOR-swizzled source k-granule
  int lq = l >> 4;                              // 0..3
  int lr = l & 15;
  int lx = l & 7;
  for (int k0 = 0; k0 < D_IN; k0 += 64) {
#pragma unroll
    for (int i = 0; i < 4; ++i) {
      __builtin_amdgcn_global_load_lds(
          (const __attribute__((address_space(1))) void*)(Ab + (size_t)(rr + i * 32) * D_IN + k0 + ccs),
          (__attribute__((address_space(3))) void*)(As + i * 2048 + t * 8),
          16, 0, 0);
    }
#pragma unroll
    for (int i = 0; i < 4; ++i) {
      __builtin_amdgcn_global_load_lds(
          (const __attribute__((address_space(1))) void*)(Bb + (size_t)(rr + i * 32) * D_IN + k0 + ccs),
          (__attribute__((address_space(3))) void*)(Bs + i * 2048 + t * 8),
          16, 0, 0);
    }
    __syncthreads();
#pragma unroll
    for (int ks = 0; ks < 2; ++ks) {
      int gsw = ((ks * 4 + lq) ^ lx) * 8;       // swizzled granule offset (ushorts)
      bf16x8 af[4], bfv[4];
#pragma unroll
      for (int fm = 0; fm < 4; ++fm)
        af[fm] = *(const bf16x8*)(As + (wm * 64 + fm * 16 + lr) * 64 + gsw);
#pragma unroll
      for (int fn = 0; fn < 4; ++fn)
        bfv[fn] = *(const bf16x8*)(Bs + (wn * 64 + fn * 16 + lr) * 64 + gsw);
#pragma unroll
      for (int fm = 0; fm < 4; ++fm)
#pragma unroll
        for (int fn = 0; fn < 4; ++fn)
          acc[fm][fn] = __builtin_amdgcn_mfma_f32_16x16x32_bf16(af[fm], bfv[fn], acc[fm][fn], 0, 0, 0);
    }
    __syncthreads();
  }
  float bev[4];
#pragma unroll
  for (int fn = 0; fn < 4; ++fn)
    bev[fn] = be[e * H_DIM + nh * 128 + wn * 64 + fn * 16 + lr];
#pragma unroll
  for (int fm = 0; fm < 4; ++fm) {
#pragma unroll
    for (int fn = 0; fn < 4; ++fn) {
      int col = nh * 128 + wn * 64 + fn * 16 + lr;
#pragma unroll
      for (int j = 0; j < 4; ++j) {
        int row = m0 + wm * 64 + fm * 16 + lq * 4 + j;
        float vv = fmaxf(acc[fm][fn][j] + bev[fn], 0.f);
        E[(size_t)row * (N_EXP * H_DIM) + e * H_DIM + col] = f2bf(vv);
      }
    }
  }
}

// ---------------------------------------------------------------------------
// Kernel 4: combine. towers[t][b][h] = sum_e G[b][t][e] * E[b][e][h]
// one wave per row, lanes cover h (4 each), float4 I/O.
// ---------------------------------------------------------------------------
__global__ void k_combine(const unsigned short* __restrict__ E, const float* __restrict__ G,
                          float* __restrict__ out) {
  int t = threadIdx.x;
  int wv = t >> 6, l = t & 63;
  int r = blockIdx.x * 4 + wv;
  const unsigned short* er = E + (size_t)r * (N_EXP * H_DIM);
  const float* g = G + (size_t)r * 32;
  float acc[4][4];
#pragma unroll
  for (int i = 0; i < 4; ++i)
#pragma unroll
    for (int j = 0; j < 4; ++j) acc[i][j] = 0.f;
#pragma unroll
  for (int e = 0; e < 8; ++e) {
    ushort4 u = *(const ushort4*)(er + e * H_DIM + l * 4);
    float f0 = bf2f(u.x), f1 = bf2f(u.y), f2 = bf2f(u.z), f3 = bf2f(u.w);
#pragma unroll
    for (int tk = 0; tk < 4; ++tk) {
      float gv = g[tk * 8 + e];
      acc[tk][0] += gv * f0;
      acc[tk][1] += gv * f1;
      acc[tk][2] += gv * f2;
      acc[tk][3] += gv * f3;
    }
  }
#pragma unroll
  for (int tk = 0; tk < 4; ++tk) {
    float4 o = make_float4(acc[tk][0], acc[tk][1], acc[tk][2], acc[tk][3]);
    *(float4*)(out + ((size_t)tk * B_ROWS + r) * H_DIM + l * 4) = o;
  }
}

extern "C" void kernel_launch(void* const* d_in, const int* in_sizes, int n_in,
                              void* d_out, int out_size, void* d_ws, size_t ws_size,
                              hipStream_t stream) {
  const float* x  = (const float*)d_in[0];
  const float* We = (const float*)d_in[1];
  const float* be = (const float*)d_in[2];
  const float* Wg = (const float*)d_in[3];
  const float* bg = (const float*)d_in[4];
  float* out = (float*)d_out;
  char* ws = (char*)d_ws;
  unsigned short* x_b  = (unsigned short*)(ws + WS_XB);
  unsigned short* We_t = (unsigned short*)(ws + WS_WET);
  unsigned short* Wg_t = (unsigned short*)(ws + WS_WGT);
  float*          G    = (float*)(ws + WS_G);
  unsigned short* E    = (unsigned short*)(ws + WS_E);

  hipMemsetAsync(G, 0, (size_t)B_ROWS * 32 * sizeof(float), stream);
  k_prep_w<<<513, 256, 0, stream>>>(We, Wg, We_t, Wg_t);
  k_gates<<<dim3(B_ROWS / 64, 4), 256, 0, stream>>>(x, Wg_t, x_b, G);
  k_expert<<<(B_ROWS / 128) * N_EXP * 2 + 64, 256, 0, stream>>>(x_b, We_t, be, bg, G, E);
  k_combine<<<B_ROWS / 4, 256, 0, stream>>>(E, G, out);
}